// Round 1
// baseline (83.970 us; speedup 1.0000x reference)
//
#include <hip/hip_runtime.h>

__device__ __forceinline__ float frelu(float x) { return fmaxf(x, 0.0f); }

// rerelu: 24-term piecewise-linear (exact in fp32 — all active (x-b) diffs and
// partial sums are exactly representable; order-independent)
__device__ float rerelu_f(float x) {
    const float o[24] = {3.25f, 3.75f, 5.25f, 5.75f, 6.25f, 6.75f, 11.25f, 11.75f,
                         15.25f, 15.75f, 20.25f, 20.75f, 23.25f, 23.75f, 35.25f, 35.75f,
                         40.25f, 40.75f, 43.25f, 43.75f, 49.25f, 49.75f, 61.25f, 61.75f};
    const float c[24] = {4.f, -4.f, -4.f, 4.f, 4.f, -4.f, -2.f, 2.f, 2.f, -2.f,
                         -2.f, 2.f, 2.f, -2.f, -2.f, 2.f, 2.f, -2.f, -2.f, 2.f,
                         2.f, -2.f, -2.f, 2.f};
    float s = 0.0f;
#pragma unroll
    for (int k = 0; k < 24; ++k) s += c[k] * frelu(x - o[k]);
    return s;
}

// rerelu2: gate in [0,1]; plateaus are EXACTLY 0/1 in fp32
__device__ float rerelu2_f(float x) {
    const float o[6] = {1.25f, 1.75f, 2.25f, 2.75f, 3.25f, 3.75f};
    const float c[6] = {-2.f, 2.f, 2.f, -2.f, -2.f, 2.f};
    float s = 0.0f;
#pragma unroll
    for (int k = 0; k < 6; ++k) s += c[k] * frelu(x - o[k]);
    return 1.0f + s;
}

__device__ __forceinline__ float rerelu3_f(float x) {
    return 2.0f * frelu(x - 1.25f) - 2.0f * frelu(x - 1.75f);
}

__device__ __forceinline__ float rerelu4_f(float x) {
    float s = 8.0f * frelu(x);
    s += -8.0f * frelu(x - 1.0f);
    s += -0.3f * frelu(x - 1.0f);
    s += 0.3f * frelu(x - 21.0f);
    return s;
}

// Kernel 1: single block. Block-scan durations; per-token dcp/ndc/v/C.
__global__ __launch_bounds__(256) void AC_tok_kernel(
    const int* __restrict__ dur, const float* __restrict__ token, int T,
    float* __restrict__ dcp, float* __restrict__ ndc, float* __restrict__ nt,
    int* __restrict__ C) {
    const int tid = threadIdx.x;
    const int items = (T + 255) >> 8;
    const int start = tid * items;
    const int end = min(start + items, T);

    int lsum = 0;
    for (int i = start; i < end; ++i) lsum += dur[i];

    __shared__ int ss[256];
    ss[tid] = lsum;
    __syncthreads();
    int inc = lsum;
    for (int off = 1; off < 256; off <<= 1) {
        int add = (tid >= off) ? ss[tid - off] : 0;
        __syncthreads();
        inc += add;
        ss[tid] = inc;
        __syncthreads();
    }
    int run = inc - lsum;  // exclusive prefix of this thread's chunk

    for (int i = start; i < end; ++i) {
        int d = dur[i];
        float dcpf = (float)run;  // exact: run < 2^15
        dcp[i] = dcpf;
        run += d;
        C[i] = run;

        float tk = rerelu_f(token[i]);
        float tkn = (i + 1 < T) ? rerelu_f(token[i + 1]) : 0.0f;
        nt[i] = rerelu3_f(tk);
        float gate = rerelu2_f(tk + tkn);                  // exactly 0/1 on plateaus
        float pd = (i + 1 < T) ? (float)dur[i + 1] : 0.0f;
        float nd = gate * pd + (float)d;                   // product exact -> fma-safe
        ndc[i] = dcpf + nd;                                // single rounding, matches ref
    }
}

// Kernel 2: each 128-thread half-block handles one output frame l.
__global__ __launch_bounds__(256) void AC_mel_kernel(
    const float* __restrict__ dcp, const float* __restrict__ ndc,
    const float* __restrict__ nt, const int* __restrict__ C, int T, int L,
    float* __restrict__ out) {
    int pos = blockIdx.x * 2 + (threadIdx.x >> 7);
    int col = threadIdx.x & 127;
    if (pos >= L) return;

    // first t with C[t] > pos  (C non-decreasing)
    int lo = 0, hi = T;
    while (lo < hi) {
        int mid = (lo + hi) >> 1;
        if (C[mid] > pos) hi = mid; else lo = mid + 1;
    }

    float lf = (float)pos;
    float S = 0.0f;
#pragma unroll
    for (int j = 0; j < 2; ++j) {
        int t = lo - 1 + j;
        if (t >= 0 && t < T) {
            float a = dcp[t], b = ndc[t];
            if (lf >= a && lf < b) {
                float v = nt[t];
                float k = (lf - a) + 1.0f;  // exact integer
                S += (k * v) * v;           // matches ref's cumsum*mel_temp association
            }
        }
    }
    out[(size_t)pos * 128 + col] = rerelu4_f(S);
}

extern "C" void kernel_launch(void* const* d_in, const int* in_sizes, int n_in,
                              void* d_out, int out_size, void* d_ws, size_t ws_size,
                              hipStream_t stream) {
    const int* dur = (const int*)d_in[0];
    const float* token = (const float*)d_in[1];
    // d_in[2] = f0 (unused by reference forward)
    float* out = (float*)d_out;
    int T = in_sizes[0];
    int L = out_size / 128;

    float* ws = (float*)d_ws;
    float* dcp = ws;
    float* ndc = ws + T;
    float* nt = ws + 2 * T;
    int* C = (int*)(ws + 3 * T);

    AC_tok_kernel<<<1, 256, 0, stream>>>(dur, token, T, dcp, ndc, nt, C);
    int nb = (L + 1) / 2;
    AC_mel_kernel<<<nb, 256, 0, stream>>>(dcp, ndc, nt, C, T, L, out);
}